// Round 11
// baseline (436.697 us; speedup 1.0000x reference)
//
#include <hip/hip_runtime.h>

#define LEAKY(v) ((v) >= 0.0f ? (v) : 0.2f * (v))

typedef __attribute__((ext_vector_type(8))) short bf16x8;
typedef __attribute__((ext_vector_type(4))) float f32x4;

__device__ __forceinline__ unsigned short f2bf(float f) {
    unsigned int u = __float_as_uint(f);
    unsigned int r = u + 0x7FFFu + ((u >> 16) & 1u);
    return (unsigned short)(r >> 16);
}
__device__ __forceinline__ unsigned int pk2(float a, float b) {
    return (unsigned int)f2bf(a) | ((unsigned int)f2bf(b) << 16);
}
__device__ __forceinline__ float lo16(unsigned int u) { return __uint_as_float(u << 16); }
__device__ __forceinline__ float hi16(unsigned int u) { return __uint_as_float(u & 0xFFFF0000u); }

// ---------------- CSR build ----------------

__global__ __launch_bounds__(256) void count_deg(const int* ei, int* deg, int E, int Etot) {
    int i = blockIdx.x * 256 + threadIdx.x;
    if (i >= Etot) return;
    int d = (i < E) ? ei[E + i] : (i - E);
    atomicAdd(&deg[d], 1);
}

__global__ __launch_bounds__(512) void scan_block(const int* deg, int* excl, int* bsum, int n) {
    __shared__ int s[512];
    int t = threadIdx.x;
    int i = blockIdx.x * 512 + t;
    int v = (i < n) ? deg[i] : 0;
    s[t] = v;
    __syncthreads();
    for (int d = 1; d < 512; d <<= 1) {
        int x = 0;
        if (t >= d) x = s[t - d];
        __syncthreads();
        if (t >= d) s[t] += x;
        __syncthreads();
    }
    if (i < n) excl[i] = s[t] - v;
    if (t == 511) bsum[blockIdx.x] = s[511];
}

__global__ __launch_bounds__(512) void scan_sums(const int* bsum, int* boff, int nb) {
    __shared__ int s[512];
    int t = threadIdx.x;
    int v = (t < nb) ? bsum[t] : 0;
    s[t] = v;
    __syncthreads();
    for (int d = 1; d < 512; d <<= 1) {
        int x = 0;
        if (t >= d) x = s[t - d];
        __syncthreads();
        if (t >= d) s[t] += x;
        __syncthreads();
    }
    boff[t] = s[t] - v;
}

__global__ __launch_bounds__(256) void finalize_off(int* csr, int* cursor, const int* boff, int n, int etot) {
    int i = blockIdx.x * 256 + threadIdx.x;
    if (i < n) {
        int v = csr[i] + boff[i >> 9];
        csr[i] = v;
        cursor[i] = v;
    }
    if (i == 0) csr[n] = etot;
}

__global__ __launch_bounds__(256) void scatter_edge(const int* ei, int* cursor, int* srcs, int* dsts,
                                                    int E, int Etot) {
    int i = blockIdx.x * 256 + threadIdx.x;
    if (i >= Etot) return;
    int s, d;
    if (i < E) { s = ei[i]; d = ei[E + i]; }
    else       { s = i - E; d = s; }
    int pos = atomicAdd(&cursor[d], 1);
    srcs[pos] = s;
    dsts[pos] = d;
}

// ---------------- weight packing ----------------
// W1 (f32 [2][128][256]) -> wt1 (bf16 [2][256 c][128 k], transposed, swizzled)

__global__ __launch_bounds__(256) void wpack(const float* __restrict__ W1, unsigned short* __restrict__ wt1) {
    int id = blockIdx.x * 256 + threadIdx.x;
    if (id >= 8192) return;
    int conv = id >> 12, rem = id & 4095;
    int c = rem >> 4, q = rem & 15;
    const float* src = W1 + (size_t)conv * 32768 + (size_t)(q * 8) * 256 + c;
    float w[8];
#pragma unroll
    for (int j = 0; j < 8; ++j) w[j] = src[j * 256];
    uint4 v;
    v.x = pk2(w[0], w[1]); v.y = pk2(w[2], w[3]);
    v.z = pk2(w[4], w[5]); v.w = pk2(w[6], w[7]);
    *(uint4*)(wt1 + (size_t)conv * 32768 + c * 128 + ((q ^ (c & 7)) << 3)) = v;
}

// ---------------- GEMM1 MFMA (fused f32->bf16 staging + fused alpha) ----------------
// block: 64 rows x 256 cols; 4 waves, wave w = head w
// SWAPPED mfma operands -> C^T register layout: thread holds 4 consecutive c per (mt,nt)
// hp layout: [n][conv(2)][head(4)][c(64)] bf16  (1 KB per node)
// aad layout: [n][16] f32: [0..7]=as (conv*4+head), [8..15]=ad

__global__ __launch_bounds__(256) void gemm1_mfma(const float* __restrict__ x_list,
                                                  const unsigned short* __restrict__ wt1,
                                                  const float* __restrict__ asw, const float* __restrict__ adw,
                                                  unsigned short* __restrict__ hp,
                                                  float* __restrict__ aad, int N) {
    __shared__ unsigned short As[64 * 128];    // 16 KB swizzled
    __shared__ unsigned short Ws[256 * 128];   // 64 KB swizzled
    int conv = blockIdx.y;
    int t = threadIdx.x;
    int w = t >> 6, l = t & 63;

    const float* xg = x_list + (size_t)conv * N * 128;
#pragma unroll
    for (int p = 0; p < 4; ++p) {
        int id = p * 256 + t;
        int row = id >> 4, q = id & 15;
        int grow = blockIdx.x * 64 + row;
        uint4 v = make_uint4(0, 0, 0, 0);
        if (grow < N) {
            const float* src = xg + (size_t)grow * 128 + q * 8;
            float4 a = *(const float4*)src;
            float4 b = *(const float4*)(src + 4);
            v.x = pk2(a.x, a.y); v.y = pk2(a.z, a.w);
            v.z = pk2(b.x, b.y); v.w = pk2(b.z, b.w);
        }
        *(uint4*)(As + row * 128 + ((q ^ (row & 7)) << 3)) = v;
    }
    const uint4* wsrc = (const uint4*)(wt1 + (size_t)conv * 32768);
#pragma unroll
    for (int p = 0; p < 16; ++p) {
        int id = p * 256 + t;
        *(uint4*)(Ws + (size_t)id * 8) = wsrc[id];
    }
    __syncthreads();

    f32x4 acc[4][4];
#pragma unroll
    for (int mt = 0; mt < 4; ++mt)
#pragma unroll
        for (int nt = 0; nt < 4; ++nt) acc[mt][nt] = (f32x4){0.f, 0.f, 0.f, 0.f};

    int lr = l & 15, lg = l >> 4;
#pragma unroll
    for (int s = 0; s < 4; ++s) {
        int kq = s * 4 + lg;
        bf16x8 af[4], bf[4];
#pragma unroll
        for (int mt = 0; mt < 4; ++mt) {
            int r = mt * 16 + lr;
            af[mt] = *(const bf16x8*)(As + r * 128 + ((kq ^ (r & 7)) << 3));
        }
#pragma unroll
        for (int nt = 0; nt < 4; ++nt) {
            int c = w * 64 + nt * 16 + lr;
            bf[nt] = *(const bf16x8*)(Ws + c * 128 + ((kq ^ (c & 7)) << 3));
        }
        // swapped operands: D = (Wcols x K) . (K x Xrows) = C^T
#pragma unroll
        for (int mt = 0; mt < 4; ++mt)
#pragma unroll
            for (int nt = 0; nt < 4; ++nt)
                acc[mt][nt] = __builtin_amdgcn_mfma_f32_16x16x32_bf16(bf[nt], af[mt], acc[mt][nt], 0, 0, 0);
    }

    // epilogue: acc[mt][nt][i]: row = bm*64+mt*16+lr, c = nt*16+lg*4+i (consecutive i!)
    float4 aswv[4], adwv[4];
#pragma unroll
    for (int nt = 0; nt < 4; ++nt) {
        aswv[nt] = *(const float4*)(asw + conv * 256 + w * 64 + nt * 16 + lg * 4);
        adwv[nt] = *(const float4*)(adw + conv * 256 + w * 64 + nt * 16 + lg * 4);
    }
#pragma unroll
    for (int mt = 0; mt < 4; ++mt) {
        int grow = blockIdx.x * 64 + mt * 16 + lr;
        bool ok = grow < N;
        float sv = 0.f, dv = 0.f;
#pragma unroll
        for (int nt = 0; nt < 4; ++nt) {
            f32x4 a = acc[mt][nt];
            if (ok) {
                uint2 pk;
                pk.x = pk2(a[0], a[1]);
                pk.y = pk2(a[2], a[3]);
                *(uint2*)(hp + (size_t)grow * 512 + conv * 256 + w * 64 + nt * 16 + lg * 4) = pk;
            }
            sv += a[0] * aswv[nt].x + a[1] * aswv[nt].y + a[2] * aswv[nt].z + a[3] * aswv[nt].w;
            dv += a[0] * adwv[nt].x + a[1] * adwv[nt].y + a[2] * adwv[nt].z + a[3] * adwv[nt].w;
        }
        sv += __shfl_xor(sv, 16); sv += __shfl_xor(sv, 32);
        dv += __shfl_xor(dv, 16); dv += __shfl_xor(dv, 32);
        if (l < 16 && ok) {
            aad[(size_t)grow * 16 + conv * 4 + w]     = sv;
            aad[(size_t)grow * 16 + 8 + conv * 4 + w] = dv;
        }
    }
}

// ---------------- edge-parallel softmax weights from aad: pw[e][ch(8)] ----------------

__global__ __launch_bounds__(256) void edge_w1(const int* __restrict__ srcs, const int* __restrict__ dsts,
                                               const float* __restrict__ aad,
                                               float* __restrict__ pw, int Etot) {
    int e = blockIdx.x * 256 + threadIdx.x;
    if (e >= Etot) return;
    int s = srcs[e], d = dsts[e];
    float4 as_lo = *(const float4*)(aad + (size_t)s * 16);
    float4 as_hi = *(const float4*)(aad + (size_t)s * 16 + 4);
    float4 ad_lo = *(const float4*)(aad + (size_t)d * 16 + 8);
    float4 ad_hi = *(const float4*)(aad + (size_t)d * 16 + 12);
    float4 p0, p1;
    p0.x = __expf(LEAKY(as_lo.x + ad_lo.x));
    p0.y = __expf(LEAKY(as_lo.y + ad_lo.y));
    p0.z = __expf(LEAKY(as_lo.z + ad_lo.z));
    p0.w = __expf(LEAKY(as_lo.w + ad_lo.w));
    p1.x = __expf(LEAKY(as_hi.x + ad_hi.x));
    p1.y = __expf(LEAKY(as_hi.y + ad_hi.y));
    p1.z = __expf(LEAKY(as_hi.z + ad_hi.z));
    p1.w = __expf(LEAKY(as_hi.w + ad_hi.w));
    *(float4*)(pw + (size_t)e * 8)     = p0;
    *(float4*)(pw + (size_t)e * 8 + 4) = p1;
}

// ---------------- layer-1 aggregate + fused layer-2 GEMM row ----------------
// wave per node; lane = ch*8 + c8 (ch = conv*4+head); lane reads hp row bytes [lane*16, +16)
// epilogue: x2 row (8 f32/lane, k = lane*8+q) @ W2 [512,16] -> h2[n][16], as2, ad2

__global__ __launch_bounds__(256) void agg1_fused(const unsigned short* __restrict__ hp,
                                                  const float* __restrict__ pw,
                                                  const int* __restrict__ off, const int* __restrict__ srcs,
                                                  const float* __restrict__ b1,
                                                  const float* __restrict__ W2,
                                                  const float* __restrict__ asw2, const float* __restrict__ adw2,
                                                  float* __restrict__ h2,
                                                  float* __restrict__ as2, float* __restrict__ ad2, int N) {
    int n = blockIdx.x * 4 + (threadIdx.x >> 6);
    int lane = threadIdx.x & 63;
    if (n >= N) return;
    int r0 = off[n], r1 = off[n + 1];
    int ch = lane >> 3;   // conv*4 + head

    float acc[8] = {0.f, 0.f, 0.f, 0.f, 0.f, 0.f, 0.f, 0.f};
    float den = 0.f;

    for (int base = r0; base < r1; base += 64) {
        int cnt = min(64, r1 - base);
        int my = (base + lane < r1) ? srcs[base + lane] : 0;
        int j = 0;
        for (; j + 2 <= cnt; j += 2) {
            int s0 = __shfl(my, j);
            int s1 = __shfl(my, j + 1);
            uint4 g0 = *(const uint4*)(hp + (size_t)s0 * 512 + lane * 8);
            uint4 g1 = *(const uint4*)(hp + (size_t)s1 * 512 + lane * 8);
            float p0 = pw[(size_t)(base + j) * 8 + ch];
            float p1 = pw[(size_t)(base + j + 1) * 8 + ch];
            den += p0; den += p1;
            acc[0] += p0 * lo16(g0.x); acc[1] += p0 * hi16(g0.x);
            acc[2] += p0 * lo16(g0.y); acc[3] += p0 * hi16(g0.y);
            acc[4] += p0 * lo16(g0.z); acc[5] += p0 * hi16(g0.z);
            acc[6] += p0 * lo16(g0.w); acc[7] += p0 * hi16(g0.w);
            acc[0] += p1 * lo16(g1.x); acc[1] += p1 * hi16(g1.x);
            acc[2] += p1 * lo16(g1.y); acc[3] += p1 * hi16(g1.y);
            acc[4] += p1 * lo16(g1.z); acc[5] += p1 * hi16(g1.z);
            acc[6] += p1 * lo16(g1.w); acc[7] += p1 * hi16(g1.w);
        }
        if (j < cnt) {
            int s0 = __shfl(my, j);
            uint4 g0 = *(const uint4*)(hp + (size_t)s0 * 512 + lane * 8);
            float p0 = pw[(size_t)(base + j) * 8 + ch];
            den += p0;
            acc[0] += p0 * lo16(g0.x); acc[1] += p0 * hi16(g0.x);
            acc[2] += p0 * lo16(g0.y); acc[3] += p0 * hi16(g0.y);
            acc[4] += p0 * lo16(g0.z); acc[5] += p0 * hi16(g0.z);
            acc[6] += p0 * lo16(g0.w); acc[7] += p0 * hi16(g0.w);
        }
    }

    // x2 row values (f32), k = lane*8 + q
    float inv = 1.f / (den + 1e-16f);
    const float* bp = b1 + lane * 8;
#pragma unroll
    for (int q = 0; q < 8; ++q) {
        float o = acc[q] * inv + bp[q];
        acc[q] = o > 0.f ? o : (__expf(o) - 1.0f);
    }

    // fused layer-2: part[c2] = sum_q acc[q] * W2[(lane*8+q)*16 + c2]
    float part[16];
#pragma unroll
    for (int c = 0; c < 16; ++c) part[c] = 0.f;
    const float* w2p = W2 + (size_t)lane * 128;   // 8 rows x 16
#pragma unroll
    for (int q = 0; q < 8; ++q) {
        float x = acc[q];
        const float* wr = w2p + q * 16;
#pragma unroll
        for (int c4 = 0; c4 < 4; ++c4) {
            float4 wv = *(const float4*)(wr + c4 * 4);
            part[c4 * 4 + 0] += x * wv.x;
            part[c4 * 4 + 1] += x * wv.y;
            part[c4 * 4 + 2] += x * wv.z;
            part[c4 * 4 + 3] += x * wv.w;
        }
    }
#pragma unroll
    for (int o = 1; o < 64; o <<= 1) {
#pragma unroll
        for (int c = 0; c < 16; ++c) part[c] += __shfl_xor(part[c], o);
    }

    if (lane == 0) {
        float4 a2lo = *(const float4*)(asw2);
        float4 a2hi = *(const float4*)(asw2 + 4);
        float4 a2l2 = *(const float4*)(asw2 + 8);
        float4 a2h2 = *(const float4*)(asw2 + 12);
        float4 d2lo = *(const float4*)(adw2);
        float4 d2hi = *(const float4*)(adw2 + 4);
        float4 d2l2 = *(const float4*)(adw2 + 8);
        float4 d2h2 = *(const float4*)(adw2 + 12);
        float sv = part[0] * a2lo.x + part[1] * a2lo.y + part[2] * a2lo.z + part[3] * a2lo.w
                 + part[4] * a2hi.x + part[5] * a2hi.y + part[6] * a2hi.z + part[7] * a2hi.w
                 + part[8] * a2l2.x + part[9] * a2l2.y + part[10] * a2l2.z + part[11] * a2l2.w
                 + part[12] * a2h2.x + part[13] * a2h2.y + part[14] * a2h2.z + part[15] * a2h2.w;
        float dv = part[0] * d2lo.x + part[1] * d2lo.y + part[2] * d2lo.z + part[3] * d2lo.w
                 + part[4] * d2hi.x + part[5] * d2hi.y + part[6] * d2hi.z + part[7] * d2hi.w
                 + part[8] * d2l2.x + part[9] * d2l2.y + part[10] * d2l2.z + part[11] * d2l2.w
                 + part[12] * d2h2.x + part[13] * d2h2.y + part[14] * d2h2.z + part[15] * d2h2.w;
        float* ho = h2 + (size_t)n * 16;
        *(float4*)(ho)      = make_float4(part[0], part[1], part[2], part[3]);
        *(float4*)(ho + 4)  = make_float4(part[4], part[5], part[6], part[7]);
        *(float4*)(ho + 8)  = make_float4(part[8], part[9], part[10], part[11]);
        *(float4*)(ho + 12) = make_float4(part[12], part[13], part[14], part[15]);
        as2[n] = sv;
        ad2[n] = dv;
    }
}

// ---------------- layer-2 aggregate, inline softmax, 16 edges in flight -> out ----------------

__global__ __launch_bounds__(256) void agg2(const float* __restrict__ h2,
                                            const float* __restrict__ as2, const float* __restrict__ ad2,
                                            const int* __restrict__ off, const int* __restrict__ srcs,
                                            const float* __restrict__ bias2, float* __restrict__ out, int N) {
    int n = blockIdx.x * 4 + (threadIdx.x >> 6);
    int lane = threadIdx.x & 63;
    if (n >= N) return;
    int r0 = off[n], r1 = off[n + 1];
    float adn = ad2[n];
    int cg = lane & 3, eo = lane >> 2;   // 16 edges in flight x 4 channel-groups

    float4 acc = make_float4(0.f, 0.f, 0.f, 0.f);
    float den = 0.f;
    for (int base = r0; base + eo < r1; base += 16) {
        int e = base + eo;
        int s = srcs[e];
        float p = __expf(LEAKY(as2[s] + adn));
        float4 hv = *(const float4*)(h2 + (size_t)s * 16 + cg * 4);
        den += p;
        acc.x += p * hv.x; acc.y += p * hv.y;
        acc.z += p * hv.z; acc.w += p * hv.w;
    }
#pragma unroll
    for (int o = 4; o < 64; o <<= 1) {
        acc.x += __shfl_xor(acc.x, o);
        acc.y += __shfl_xor(acc.y, o);
        acc.z += __shfl_xor(acc.z, o);
        acc.w += __shfl_xor(acc.w, o);
        den   += __shfl_xor(den, o);
    }
    if (eo == 0) {
        float inv = 1.f / (den + 1e-16f);
        float4 b = *(const float4*)(bias2 + cg * 4);
        float4 o4;
        o4.x = acc.x * inv + b.x;
        o4.y = acc.y * inv + b.y;
        o4.z = acc.z * inv + b.z;
        o4.w = acc.w * inv + b.w;
        *(float4*)(out + (size_t)n * 16 + cg * 4) = o4;
    }
}

// ---------------- launch ----------------

extern "C" void kernel_launch(void* const* d_in, const int* in_sizes, int n_in,
                              void* d_out, int out_size, void* d_ws, size_t ws_size,
                              hipStream_t stream) {
    const float* x_list = (const float*)d_in[0];   // [2, N, 128]
    const int*   ei     = (const int*)d_in[1];     // [2, E] int32
    const float* W1     = (const float*)d_in[2];   // [2, 128, 256]
    const float* as1w   = (const float*)d_in[3];   // [2, 4, 64]
    const float* ad1w   = (const float*)d_in[4];
    const float* b1     = (const float*)d_in[5];   // [2, 256]
    const float* W2     = (const float*)d_in[6];   // [512, 16]
    const float* as2w   = (const float*)d_in[7];
    const float* ad2w   = (const float*)d_in[8];
    const float* b2     = (const float*)d_in[9];   // [16]
    float* out = (float*)d_out;

    const int N = in_sizes[0] / 256;   // 50000
    const int E = in_sizes[1] / 2;     // 800000
    const int Etot = E + N;

    char* ws = (char*)d_ws;
    size_t woff = 0;
    auto alloc = [&](size_t bytes) {
        char* p = ws + woff;
        woff = (woff + bytes + 255) & ~(size_t)255;
        return p;
    };
    int*   csr    = (int*)alloc((size_t)(N + 1) * 4);
    int*   cursor = (int*)alloc((size_t)N * 4);
    int*   srcs   = (int*)alloc((size_t)Etot * 4);
    int*   dsts   = (int*)alloc((size_t)Etot * 4);
    int*   bsum   = (int*)alloc(512 * 4);
    int*   boff   = (int*)alloc(512 * 4);
    float* aad    = (float*)alloc((size_t)N * 16 * 4);   // [n][as(8) | ad(8)], 3.2 MB
    float* as2    = (float*)alloc((size_t)N * 4);
    float* ad2    = (float*)alloc((size_t)N * 4);
    unsigned short* wt1 = (unsigned short*)alloc(2 * 32768 * 2);
    unsigned short* hp  = (unsigned short*)alloc((size_t)N * 512 * 2);   // [n][conv][head][c] bf16, 51.2 MB
    float* h2     = (float*)alloc((size_t)N * 16 * 4);
    float* pw     = (float*)alloc((size_t)Etot * 8 * 4);  // 27.2 MB

    // CSR by dst
    hipMemsetAsync(cursor, 0, (size_t)N * 4, stream);
    int gE = (Etot + 255) / 256;
    count_deg<<<gE, 256, 0, stream>>>(ei, cursor, E, Etot);
    int nb = (N + 511) / 512;
    scan_block<<<nb, 512, 0, stream>>>(cursor, csr, bsum, N);
    scan_sums<<<1, 512, 0, stream>>>(bsum, boff, nb);
    finalize_off<<<(N + 255) / 256, 256, 0, stream>>>(csr, cursor, boff, N, Etot);
    scatter_edge<<<gE, 256, 0, stream>>>(ei, cursor, srcs, dsts, E, Etot);

    wpack<<<32, 256, 0, stream>>>(W1, wt1);

    // layer 1 (+ fused layer-2 GEMM in agg epilogue)
    gemm1_mfma<<<dim3((N + 63) / 64, 2), 256, 0, stream>>>(x_list, wt1, as1w, ad1w, hp, aad, N);
    edge_w1<<<gE, 256, 0, stream>>>(srcs, dsts, aad, pw, Etot);
    agg1_fused<<<(N + 3) / 4, 256, 0, stream>>>(hp, pw, csr, srcs, b1, W2, as2w, ad2w,
                                                h2, as2, ad2, N);

    // layer 2 aggregate
    agg2<<<(N + 3) / 4, 256, 0, stream>>>(h2, as2, ad2, csr, srcs, b2, out, N);
}

// Round 12
// 305.541 us; speedup vs baseline: 1.4293x; 1.4293x over previous
//
#include <hip/hip_runtime.h>

#define LEAKY(v) ((v) >= 0.0f ? (v) : 0.2f * (v))

typedef __attribute__((ext_vector_type(8))) short bf16x8;
typedef __attribute__((ext_vector_type(4))) float f32x4;

__device__ __forceinline__ unsigned short f2bf(float f) {
    unsigned int u = __float_as_uint(f);
    unsigned int r = u + 0x7FFFu + ((u >> 16) & 1u);
    return (unsigned short)(r >> 16);
}
__device__ __forceinline__ unsigned int pk2(float a, float b) {
    return (unsigned int)f2bf(a) | ((unsigned int)f2bf(b) << 16);
}
__device__ __forceinline__ float lo16(unsigned int u) { return __uint_as_float(u << 16); }
__device__ __forceinline__ float hi16(unsigned int u) { return __uint_as_float(u & 0xFFFF0000u); }

// ---------------- CSR build ----------------

__global__ __launch_bounds__(256) void count_deg(const int* ei, int* deg, int E, int Etot) {
    int i = blockIdx.x * 256 + threadIdx.x;
    if (i >= Etot) return;
    int d = (i < E) ? ei[E + i] : (i - E);
    atomicAdd(&deg[d], 1);
}

__global__ __launch_bounds__(512) void scan_block(const int* deg, int* excl, int* bsum, int n) {
    __shared__ int s[512];
    int t = threadIdx.x;
    int i = blockIdx.x * 512 + t;
    int v = (i < n) ? deg[i] : 0;
    s[t] = v;
    __syncthreads();
    for (int d = 1; d < 512; d <<= 1) {
        int x = 0;
        if (t >= d) x = s[t - d];
        __syncthreads();
        if (t >= d) s[t] += x;
        __syncthreads();
    }
    if (i < n) excl[i] = s[t] - v;
    if (t == 511) bsum[blockIdx.x] = s[511];
}

__global__ __launch_bounds__(512) void scan_sums(const int* bsum, int* boff, int nb) {
    __shared__ int s[512];
    int t = threadIdx.x;
    int v = (t < nb) ? bsum[t] : 0;
    s[t] = v;
    __syncthreads();
    for (int d = 1; d < 512; d <<= 1) {
        int x = 0;
        if (t >= d) x = s[t - d];
        __syncthreads();
        if (t >= d) s[t] += x;
        __syncthreads();
    }
    boff[t] = s[t] - v;
}

__global__ __launch_bounds__(256) void finalize_off(int* csr, int* cursor, const int* boff, int n, int etot) {
    int i = blockIdx.x * 256 + threadIdx.x;
    if (i < n) {
        int v = csr[i] + boff[i >> 9];
        csr[i] = v;
        cursor[i] = v;
    }
    if (i == 0) csr[n] = etot;
}

__global__ __launch_bounds__(256) void scatter_edge(const int* ei, int* cursor, int* srcs, int* dsts,
                                                    int E, int Etot) {
    int i = blockIdx.x * 256 + threadIdx.x;
    if (i >= Etot) return;
    int s, d;
    if (i < E) { s = ei[i]; d = ei[E + i]; }
    else       { s = i - E; d = s; }
    int pos = atomicAdd(&cursor[d], 1);
    srcs[pos] = s;
    dsts[pos] = d;
}

// ---------------- weight packing (merged) ----------------

__global__ __launch_bounds__(256) void wpack(const float* __restrict__ W1, unsigned short* __restrict__ wt1,
                                             const float* __restrict__ W2, unsigned short* __restrict__ wt2) {
    int id = blockIdx.x * 256 + threadIdx.x;
    if (id < 8192) {
        int conv = id >> 12, rem = id & 4095;
        int c = rem >> 4, q = rem & 15;
        const float* src = W1 + (size_t)conv * 32768 + (size_t)(q * 8) * 256 + c;
        float w[8];
#pragma unroll
        for (int j = 0; j < 8; ++j) w[j] = src[j * 256];
        uint4 v;
        v.x = pk2(w[0], w[1]); v.y = pk2(w[2], w[3]);
        v.z = pk2(w[4], w[5]); v.w = pk2(w[6], w[7]);
        *(uint4*)(wt1 + (size_t)conv * 32768 + c * 128 + ((q ^ (c & 7)) << 3)) = v;
    } else if (id < 9216) {
        int id2 = id - 8192;
        int s = id2 >> 6, l = id2 & 63;
        const float* src = W2 + (size_t)(s * 32 + (l >> 4) * 8) * 16 + (l & 15);
        float w[8];
#pragma unroll
        for (int j = 0; j < 8; ++j) w[j] = src[j * 16];
        uint4 v;
        v.x = pk2(w[0], w[1]); v.y = pk2(w[2], w[3]);
        v.z = pk2(w[4], w[5]); v.w = pk2(w[6], w[7]);
        *(uint4*)(wt2 + (size_t)id2 * 8) = v;
    }
}

// ---------------- GEMM1 MFMA (fused f32->bf16 staging + fused alpha) ----------------
// hp layout: [n][conv(2)][head(4)][c(64)] bf16; aad: [n][as(8)|ad(8)] f32

__global__ __launch_bounds__(256) void gemm1_mfma(const float* __restrict__ x_list,
                                                  const unsigned short* __restrict__ wt1,
                                                  const float* __restrict__ asw, const float* __restrict__ adw,
                                                  unsigned short* __restrict__ hp,
                                                  float* __restrict__ aad, int N) {
    __shared__ unsigned short As[64 * 128];
    __shared__ unsigned short Ws[256 * 128];
    int conv = blockIdx.y;
    int t = threadIdx.x;
    int w = t >> 6, l = t & 63;

    const float* xg = x_list + (size_t)conv * N * 128;
#pragma unroll
    for (int p = 0; p < 4; ++p) {
        int id = p * 256 + t;
        int row = id >> 4, q = id & 15;
        int grow = blockIdx.x * 64 + row;
        uint4 v = make_uint4(0, 0, 0, 0);
        if (grow < N) {
            const float* src = xg + (size_t)grow * 128 + q * 8;
            float4 a = *(const float4*)src;
            float4 b = *(const float4*)(src + 4);
            v.x = pk2(a.x, a.y); v.y = pk2(a.z, a.w);
            v.z = pk2(b.x, b.y); v.w = pk2(b.z, b.w);
        }
        *(uint4*)(As + row * 128 + ((q ^ (row & 7)) << 3)) = v;
    }
    const uint4* wsrc = (const uint4*)(wt1 + (size_t)conv * 32768);
#pragma unroll
    for (int p = 0; p < 16; ++p) {
        int id = p * 256 + t;
        *(uint4*)(Ws + (size_t)id * 8) = wsrc[id];
    }
    __syncthreads();

    f32x4 acc[4][4];
#pragma unroll
    for (int mt = 0; mt < 4; ++mt)
#pragma unroll
        for (int nt = 0; nt < 4; ++nt) acc[mt][nt] = (f32x4){0.f, 0.f, 0.f, 0.f};

    int lr = l & 15, lg = l >> 4;
#pragma unroll
    for (int s = 0; s < 4; ++s) {
        int kq = s * 4 + lg;
        bf16x8 af[4], bf[4];
#pragma unroll
        for (int mt = 0; mt < 4; ++mt) {
            int r = mt * 16 + lr;
            af[mt] = *(const bf16x8*)(As + r * 128 + ((kq ^ (r & 7)) << 3));
        }
#pragma unroll
        for (int nt = 0; nt < 4; ++nt) {
            int c = w * 64 + nt * 16 + lr;
            bf[nt] = *(const bf16x8*)(Ws + c * 128 + ((kq ^ (c & 7)) << 3));
        }
#pragma unroll
        for (int mt = 0; mt < 4; ++mt)
#pragma unroll
            for (int nt = 0; nt < 4; ++nt)
                acc[mt][nt] = __builtin_amdgcn_mfma_f32_16x16x32_bf16(bf[nt], af[mt], acc[mt][nt], 0, 0, 0);
    }

    float4 aswv[4], adwv[4];
#pragma unroll
    for (int nt = 0; nt < 4; ++nt) {
        aswv[nt] = *(const float4*)(asw + conv * 256 + w * 64 + nt * 16 + lg * 4);
        adwv[nt] = *(const float4*)(adw + conv * 256 + w * 64 + nt * 16 + lg * 4);
    }
#pragma unroll
    for (int mt = 0; mt < 4; ++mt) {
        int grow = blockIdx.x * 64 + mt * 16 + lr;
        bool ok = grow < N;
        float sv = 0.f, dv = 0.f;
#pragma unroll
        for (int nt = 0; nt < 4; ++nt) {
            f32x4 a = acc[mt][nt];
            if (ok) {
                uint2 pk;
                pk.x = pk2(a[0], a[1]);
                pk.y = pk2(a[2], a[3]);
                *(uint2*)(hp + (size_t)grow * 512 + conv * 256 + w * 64 + nt * 16 + lg * 4) = pk;
            }
            sv += a[0] * aswv[nt].x + a[1] * aswv[nt].y + a[2] * aswv[nt].z + a[3] * aswv[nt].w;
            dv += a[0] * adwv[nt].x + a[1] * adwv[nt].y + a[2] * adwv[nt].z + a[3] * adwv[nt].w;
        }
        sv += __shfl_xor(sv, 16); sv += __shfl_xor(sv, 32);
        dv += __shfl_xor(dv, 16); dv += __shfl_xor(dv, 32);
        if (l < 16 && ok) {
            aad[(size_t)grow * 16 + conv * 4 + w]     = sv;
            aad[(size_t)grow * 16 + 8 + conv * 4 + w] = dv;
        }
    }
}

// ---------------- edge-parallel softmax weights from aad: pw[e][ch(8)] ----------------

__global__ __launch_bounds__(256) void edge_w1(const int* __restrict__ srcs, const int* __restrict__ dsts,
                                               const float* __restrict__ aad,
                                               float* __restrict__ pw, int Etot) {
    int e = blockIdx.x * 256 + threadIdx.x;
    if (e >= Etot) return;
    int s = srcs[e], d = dsts[e];
    float4 as_lo = *(const float4*)(aad + (size_t)s * 16);
    float4 as_hi = *(const float4*)(aad + (size_t)s * 16 + 4);
    float4 ad_lo = *(const float4*)(aad + (size_t)d * 16 + 8);
    float4 ad_hi = *(const float4*)(aad + (size_t)d * 16 + 12);
    float4 p0, p1;
    p0.x = __expf(LEAKY(as_lo.x + ad_lo.x));
    p0.y = __expf(LEAKY(as_lo.y + ad_lo.y));
    p0.z = __expf(LEAKY(as_lo.z + ad_lo.z));
    p0.w = __expf(LEAKY(as_lo.w + ad_lo.w));
    p1.x = __expf(LEAKY(as_hi.x + ad_hi.x));
    p1.y = __expf(LEAKY(as_hi.y + ad_hi.y));
    p1.z = __expf(LEAKY(as_hi.z + ad_hi.z));
    p1.w = __expf(LEAKY(as_hi.w + ad_hi.w));
    *(float4*)(pw + (size_t)e * 8)     = p0;
    *(float4*)(pw + (size_t)e * 8 + 4) = p1;
}

// ---------------- layer-1 aggregate: per-lane (ch, c8), sequential pw, 4-deep gathers ----------------

#define ACC1(g, p) {                                           \
    den += (p);                                                \
    acc[0] += (p) * lo16((g).x); acc[1] += (p) * hi16((g).x);  \
    acc[2] += (p) * lo16((g).y); acc[3] += (p) * hi16((g).y);  \
    acc[4] += (p) * lo16((g).z); acc[5] += (p) * hi16((g).z);  \
    acc[6] += (p) * lo16((g).w); acc[7] += (p) * hi16((g).w); }

__global__ __launch_bounds__(256) void agg1_both(const unsigned short* __restrict__ hp,
                                                 const float* __restrict__ pw,
                                                 const int* __restrict__ off, const int* __restrict__ srcs,
                                                 const float* __restrict__ b1,
                                                 unsigned short* __restrict__ x2, int N) {
    int n = blockIdx.x * 4 + (threadIdx.x >> 6);
    int lane = threadIdx.x & 63;
    if (n >= N) return;
    int r0 = off[n], r1 = off[n + 1];
    int ch = lane >> 3;   // conv*4 + head

    float acc[8] = {0.f, 0.f, 0.f, 0.f, 0.f, 0.f, 0.f, 0.f};
    float den = 0.f;

    for (int base = r0; base < r1; base += 64) {
        int cnt = min(64, r1 - base);
        int my = (base + lane < r1) ? srcs[base + lane] : 0;
        int j = 0;
        for (; j + 4 <= cnt; j += 4) {
            int s0 = __shfl(my, j);
            int s1 = __shfl(my, j + 1);
            int s2 = __shfl(my, j + 2);
            int s3 = __shfl(my, j + 3);
            uint4 g0 = *(const uint4*)(hp + (size_t)s0 * 512 + lane * 8);
            uint4 g1 = *(const uint4*)(hp + (size_t)s1 * 512 + lane * 8);
            uint4 g2 = *(const uint4*)(hp + (size_t)s2 * 512 + lane * 8);
            uint4 g3 = *(const uint4*)(hp + (size_t)s3 * 512 + lane * 8);
            float p0 = pw[(size_t)(base + j) * 8 + ch];
            float p1 = pw[(size_t)(base + j + 1) * 8 + ch];
            float p2 = pw[(size_t)(base + j + 2) * 8 + ch];
            float p3 = pw[(size_t)(base + j + 3) * 8 + ch];
            ACC1(g0, p0);
            ACC1(g1, p1);
            ACC1(g2, p2);
            ACC1(g3, p3);
        }
        for (; j < cnt; ++j) {
            int s0 = __shfl(my, j);
            uint4 g0 = *(const uint4*)(hp + (size_t)s0 * 512 + lane * 8);
            float p0 = pw[(size_t)(base + j) * 8 + ch];
            ACC1(g0, p0);
        }
    }

    float inv = 1.f / (den + 1e-16f);
    const float* bp = b1 + lane * 8;
    unsigned int ow[4];
#pragma unroll
    for (int q = 0; q < 4; ++q) {
        float o0 = acc[q * 2 + 0] * inv + bp[q * 2 + 0];
        float o1 = acc[q * 2 + 1] * inv + bp[q * 2 + 1];
        o0 = o0 > 0.f ? o0 : (__expf(o0) - 1.0f);
        o1 = o1 > 0.f ? o1 : (__expf(o1) - 1.0f);
        ow[q] = pk2(o0, o1);
    }
    uint4 ov = make_uint4(ow[0], ow[1], ow[2], ow[3]);
    *(uint4*)(x2 + (size_t)n * 512 + lane * 8) = ov;
}

// ---------------- GEMM2 MFMA: x2 [N,512] @ wt2 -> h2 [N,16] + fused alpha2 ----------------

__global__ __launch_bounds__(256) void gemm2_mfma(const unsigned short* __restrict__ x2,
                                                  const unsigned short* __restrict__ wt2,
                                                  const float* __restrict__ asw2, const float* __restrict__ adw2,
                                                  float* __restrict__ h2,
                                                  float* __restrict__ as2, float* __restrict__ ad2, int N) {
    int t = threadIdx.x;
    int w = t >> 6, l = t & 63;
    int rowbase = (blockIdx.x * 4 + w) * 16;
    if (rowbase >= N) return;
    int lr = l & 15, lg = l >> 4;

    f32x4 acc = (f32x4){0.f, 0.f, 0.f, 0.f};
    const unsigned short* ap = x2 + (size_t)(rowbase + lr) * 512 + lg * 8;
#pragma unroll
    for (int s = 0; s < 16; ++s) {
        bf16x8 av = *(const bf16x8*)(ap + s * 32);
        bf16x8 bv = *(const bf16x8*)(wt2 + ((size_t)s * 64 + l) * 8);
        acc = __builtin_amdgcn_mfma_f32_16x16x32_bf16(av, bv, acc, 0, 0, 0);
    }

    float asv = asw2[lr], adv = adw2[lr];
#pragma unroll
    for (int i = 0; i < 4; ++i) {
        int row = rowbase + lg * 4 + i;
        if (row < N) h2[(size_t)row * 16 + lr] = acc[i];
        float sv = acc[i] * asv, dv = acc[i] * adv;
#pragma unroll
        for (int o = 1; o < 16; o <<= 1) {
            sv += __shfl_xor(sv, o);
            dv += __shfl_xor(dv, o);
        }
        if (lr == 0 && row < N) { as2[row] = sv; ad2[row] = dv; }
    }
}

// ---------------- layer-2 aggregate, inline softmax, 16 edges in flight -> out ----------------

__global__ __launch_bounds__(256) void agg2(const float* __restrict__ h2,
                                            const float* __restrict__ as2, const float* __restrict__ ad2,
                                            const int* __restrict__ off, const int* __restrict__ srcs,
                                            const float* __restrict__ bias2, float* __restrict__ out, int N) {
    int n = blockIdx.x * 4 + (threadIdx.x >> 6);
    int lane = threadIdx.x & 63;
    if (n >= N) return;
    int r0 = off[n], r1 = off[n + 1];
    float adn = ad2[n];
    int cg = lane & 3, eo = lane >> 2;

    float4 acc = make_float4(0.f, 0.f, 0.f, 0.f);
    float den = 0.f;
    for (int base = r0; base + eo < r1; base += 16) {
        int e = base + eo;
        int s = srcs[e];
        float p = __expf(LEAKY(as2[s] + adn));
        float4 hv = *(const float4*)(h2 + (size_t)s * 16 + cg * 4);
        den += p;
        acc.x += p * hv.x; acc.y += p * hv.y;
        acc.z += p * hv.z; acc.w += p * hv.w;
    }
#pragma unroll
    for (int o = 4; o < 64; o <<= 1) {
        acc.x += __shfl_xor(acc.x, o);
        acc.y += __shfl_xor(acc.y, o);
        acc.z += __shfl_xor(acc.z, o);
        acc.w += __shfl_xor(acc.w, o);
        den   += __shfl_xor(den, o);
    }
    if (eo == 0) {
        float inv = 1.f / (den + 1e-16f);
        float4 b = *(const float4*)(bias2 + cg * 4);
        float4 o4;
        o4.x = acc.x * inv + b.x;
        o4.y = acc.y * inv + b.y;
        o4.z = acc.z * inv + b.z;
        o4.w = acc.w * inv + b.w;
        *(float4*)(out + (size_t)n * 16 + cg * 4) = o4;
    }
}

// ---------------- launch ----------------

extern "C" void kernel_launch(void* const* d_in, const int* in_sizes, int n_in,
                              void* d_out, int out_size, void* d_ws, size_t ws_size,
                              hipStream_t stream) {
    const float* x_list = (const float*)d_in[0];   // [2, N, 128]
    const int*   ei     = (const int*)d_in[1];     // [2, E] int32
    const float* W1     = (const float*)d_in[2];   // [2, 128, 256]
    const float* as1w   = (const float*)d_in[3];   // [2, 4, 64]
    const float* ad1w   = (const float*)d_in[4];
    const float* b1     = (const float*)d_in[5];   // [2, 256]
    const float* W2     = (const float*)d_in[6];   // [512, 16]
    const float* as2w   = (const float*)d_in[7];
    const float* ad2w   = (const float*)d_in[8];
    const float* b2     = (const float*)d_in[9];   // [16]
    float* out = (float*)d_out;

    const int N = in_sizes[0] / 256;   // 50000
    const int E = in_sizes[1] / 2;     // 800000
    const int Etot = E + N;

    char* ws = (char*)d_ws;
    size_t woff = 0;
    auto alloc = [&](size_t bytes) {
        char* p = ws + woff;
        woff = (woff + bytes + 255) & ~(size_t)255;
        return p;
    };
    int*   csr    = (int*)alloc((size_t)(N + 1) * 4);
    int*   cursor = (int*)alloc((size_t)N * 4);
    int*   srcs   = (int*)alloc((size_t)Etot * 4);
    int*   dsts   = (int*)alloc((size_t)Etot * 4);
    int*   bsum   = (int*)alloc(512 * 4);
    int*   boff   = (int*)alloc(512 * 4);
    float* aad    = (float*)alloc((size_t)N * 16 * 4);   // [n][as(8) | ad(8)], 3.2 MB
    float* as2    = (float*)alloc((size_t)N * 4);
    float* ad2    = (float*)alloc((size_t)N * 4);
    unsigned short* wt1 = (unsigned short*)alloc(2 * 32768 * 2);
    unsigned short* wt2 = (unsigned short*)alloc(16 * 64 * 8 * 2);
    unsigned short* hp  = (unsigned short*)alloc((size_t)N * 512 * 2);   // 51.2 MB
    unsigned short* x2  = (unsigned short*)alloc((size_t)N * 512 * 2);   // 51.2 MB
    float* h2     = (float*)alloc((size_t)N * 16 * 4);
    float* pw     = (float*)alloc((size_t)Etot * 8 * 4);  // 27.2 MB

    // CSR by dst
    hipMemsetAsync(cursor, 0, (size_t)N * 4, stream);
    int gE = (Etot + 255) / 256;
    count_deg<<<gE, 256, 0, stream>>>(ei, cursor, E, Etot);
    int nb = (N + 511) / 512;
    scan_block<<<nb, 512, 0, stream>>>(cursor, csr, bsum, N);
    scan_sums<<<1, 512, 0, stream>>>(bsum, boff, nb);
    finalize_off<<<(N + 255) / 256, 256, 0, stream>>>(csr, cursor, boff, N, Etot);
    scatter_edge<<<gE, 256, 0, stream>>>(ei, cursor, srcs, dsts, E, Etot);

    wpack<<<36, 256, 0, stream>>>(W1, wt1, W2, wt2);

    // layer 1
    gemm1_mfma<<<dim3((N + 63) / 64, 2), 256, 0, stream>>>(x_list, wt1, as1w, ad1w, hp, aad, N);
    edge_w1<<<gE, 256, 0, stream>>>(srcs, dsts, aad, pw, Etot);
    agg1_both<<<(N + 3) / 4, 256, 0, stream>>>(hp, pw, csr, srcs, b1, x2, N);

    // layer 2
    gemm2_mfma<<<(N + 63) / 64, 256, 0, stream>>>(x2, wt2, as2w, ad2w, h2, as2, ad2, N);
    agg2<<<(N + 3) / 4, 256, 0, stream>>>(h2, as2, ad2, csr, srcs, b2, out, N);
}